// Round 14
// baseline (200.553 us; speedup 1.0000x reference)
//
#include <hip/hip_runtime.h>
#include <math.h>

#define BB 16
#define NN 2048
#define FF 64
#define SS 4
#define PP 22
#define OO 42
#define FPDIM (FF + 2*PP)   // 108
#define NREG 32             // all 2048/64 d2 values kept in VGPRs per lane

__device__ __forceinline__ float readfirstlane_f32(float v) {
    // value-preserving wave-uniform broadcast (builtin is int->int; must pass bits!)
    return __uint_as_float((unsigned)__builtin_amdgcn_readfirstlane((int)__float_as_uint(v)));
}

// canonical GCN wave64 inclusive scan via DPP: row_shr 1/2/4/8 (bound_ctrl -> OOB reads 0),
// then row_bcast:15 into rows 1,3 and row_bcast:31 into rows 2,3. [R11/R12-validated]
__device__ __forceinline__ int wave_scan_dpp(int x) {
    x += __builtin_amdgcn_update_dpp(0, x, 0x111, 0xf, 0xf, true);  // row_shr:1
    x += __builtin_amdgcn_update_dpp(0, x, 0x112, 0xf, 0xf, true);  // row_shr:2
    x += __builtin_amdgcn_update_dpp(0, x, 0x114, 0xf, 0xf, true);  // row_shr:4
    x += __builtin_amdgcn_update_dpp(0, x, 0x118, 0xf, 0xf, true);  // row_shr:8
    x += __builtin_amdgcn_update_dpp(0, x, 0x142, 0xa, 0xf, true);  // row_bcast:15 -> rows 1,3
    x += __builtin_amdgcn_update_dpp(0, x, 0x143, 0xc, 0xf, true);  // row_bcast:31 -> rows 2,3
    return x;
}
__device__ __forceinline__ int wave_sum_dpp(int x) {
    return __builtin_amdgcn_readlane(wave_scan_dpp(x), 63);
}
// float wave sum: same chain in float domain (0-bits = 0.0f additive identity)
__device__ __forceinline__ float wave_fsum_dpp(float x) {
    float t;
    t = __uint_as_float((unsigned)__builtin_amdgcn_update_dpp(0, (int)__float_as_uint(x), 0x111, 0xf, 0xf, true)); x += t;
    t = __uint_as_float((unsigned)__builtin_amdgcn_update_dpp(0, (int)__float_as_uint(x), 0x112, 0xf, 0xf, true)); x += t;
    t = __uint_as_float((unsigned)__builtin_amdgcn_update_dpp(0, (int)__float_as_uint(x), 0x114, 0xf, 0xf, true)); x += t;
    t = __uint_as_float((unsigned)__builtin_amdgcn_update_dpp(0, (int)__float_as_uint(x), 0x118, 0xf, 0xf, true)); x += t;
    t = __uint_as_float((unsigned)__builtin_amdgcn_update_dpp(0, (int)__float_as_uint(x), 0x142, 0xa, 0xf, true)); x += t;
    t = __uint_as_float((unsigned)__builtin_amdgcn_update_dpp(0, (int)__float_as_uint(x), 0x143, 0xc, 0xf, true)); x += t;
    return __uint_as_float((unsigned)__builtin_amdgcn_readlane((int)__float_as_uint(x), 63));
}

// ---------------- Kernel 1a: coords = x@W_s + b_s ; feats = x@W_f + b_f ----------------
__global__ __launch_bounds__(256) void precompute_kernel(
    const float* __restrict__ x, const float* __restrict__ Ws, const float* __restrict__ bs,
    const float* __restrict__ Wf, const float* __restrict__ bf,
    float* __restrict__ coords, float* __restrict__ feats)
{
    int row = blockIdx.x * 256 + threadIdx.x;   // 0 .. B*N-1
    if (row >= BB * NN) return;

    const float4* x4 = (const float4*)(x + (size_t)row * FF);
    float c0 = bs[0], c1 = bs[1], c2 = bs[2], c3 = bs[3];
    float f[PP];
    #pragma unroll
    for (int c = 0; c < PP; c++) f[c] = bf[c];

    #pragma unroll
    for (int k4 = 0; k4 < FF / 4; k4++) {
        float4 xv = x4[k4];
        float xs[4] = {xv.x, xv.y, xv.z, xv.w};
        #pragma unroll
        for (int r = 0; r < 4; r++) {
            int k = k4 * 4 + r;
            float xk = xs[r];
            c0 = fmaf(xk, Ws[k * SS + 0], c0);
            c1 = fmaf(xk, Ws[k * SS + 1], c1);
            c2 = fmaf(xk, Ws[k * SS + 2], c2);
            c3 = fmaf(xk, Ws[k * SS + 3], c3);
            #pragma unroll
            for (int c = 0; c < PP; c++) f[c] = fmaf(xk, Wf[k * PP + c], f[c]);
        }
    }
    float4* cp = (float4*)(coords + (size_t)row * SS);
    *cp = make_float4(c0, c1, c2, c3);
    float* fo = feats + (size_t)row * PP;
    #pragma unroll
    for (int c = 0; c < PP; c++) fo[c] = f[c];
}

// ---------------- Kernel 1b: xwo[row][o] = x[row] . Wo[:64,o] + bo[o] ----------------
// one thread per OUTPUT ELEMENT: 1.37M threads / 5376 blocks -> full chip, 64 fma each.
// Wo reads coalesced (consecutive o across lanes); x reads broadcast (42 lanes share a row).
__global__ __launch_bounds__(256) void xwo_kernel(
    const float* __restrict__ x, const float* __restrict__ Wo, const float* __restrict__ bo,
    float* __restrict__ xwo)
{
    int idx = blockIdx.x * 256 + threadIdx.x;   // row*42 + o
    if (idx >= BB * NN * OO) return;
    int row = idx / OO;
    int o   = idx - row * OO;
    const float* xr = x + (size_t)row * FF;
    float a0 = bo[o], a1 = 0.f, a2 = 0.f, a3 = 0.f;
    #pragma unroll
    for (int k4 = 0; k4 < FF / 4; k4++) {
        a0 = fmaf(xr[k4 * 4 + 0], Wo[(k4 * 4 + 0) * OO + o], a0);
        a1 = fmaf(xr[k4 * 4 + 1], Wo[(k4 * 4 + 1) * OO + o], a1);
        a2 = fmaf(xr[k4 * 4 + 2], Wo[(k4 * 4 + 2) * OO + o], a2);
        a3 = fmaf(xr[k4 * 4 + 3], Wo[(k4 * 4 + 3) * OO + o], a3);
    }
    xwo[idx] = (a0 + a1) + (a2 + a3);
}

// ---- Kernel 2: wave-per-query kNN + aggregate + fused (neighbor-part) matvec/tanh ----
// (128,4) -> 8 waves/EU. All 32 d2 in VGPRs. Quad opening probe + dual bisection (DPP sums);
// DPP scan collect; tie-rank with fast path; epilogue only covers k=64..107 (x-part hoisted).
// [R13-measured: 91us, VGPR 32, occupancy 75%]
__global__ __launch_bounds__(128, 4) void knn_out_kernel(
    const float* __restrict__ coords, const float* __restrict__ feats,
    const float* __restrict__ xwo, const float* __restrict__ Wo,
    const int* __restrict__ nnbr, float* __restrict__ out)
{
    const int lane = threadIdx.x & 63;
    const int w    = threadIdx.x >> 6;
    const int q    = blockIdx.x * 2 + w;       // 0..32767
    const int b    = q >> 11;
    const int i    = q & (NN - 1);

    int K = *nnbr; K = K < 2 ? 2 : (K > 64 ? 64 : K);

    __shared__ int   isel[2][64];
    __shared__ float wsel[2][64];
    __shared__ unsigned long long candk[2][64];   // (d2bits<<32)|j packed keys
    __shared__ __align__(16) float urow[2][48];   // [max | mean], 44 used

    // prefetch the precomputed x-part of the output (overlaps the distance phase)
    float xw = 0.f;
    if (lane < OO) xw = xwo[(size_t)q * OO + lane];

    const float4* cb = (const float4*)(coords + (size_t)b * NN * SS);
    float4 qv = cb[i];
    const float qx = readfirstlane_f32(qv.x);
    const float qy = readfirstlane_f32(qv.y);
    const float qz = readfirstlane_f32(qv.z);
    const float qw = readfirstlane_f32(qv.w);

    // ---- distances: all 2048 kept in 32 VGPRs/lane; track per-lane min ----
    float d2r[NREG];
    float lmin = INFINITY;
    #pragma unroll 4
    for (int r = 0; r < NREG; r++) {
        float4 c = cb[r * 64 + lane];
        float d0 = qx - c.x, d1 = qy - c.y, d2 = qz - c.z, d3 = qw - c.w;
        float v = d0 * d0 + d1 * d1 + d2 * d2 + d3 * d3;
        d2r[r] = v;
        lmin = fminf(lmin, v);
    }

    // ---- first-probe estimator: mean of per-lane minima ~ K/N quantile (DPP sum) ----
    float t0 = wave_fsum_dpp(lmin) * (1.0f / 64.0f);

    // ---- selection state: invariant cnt_lt(lo) < K <= cnt_lt(hi) ----
    unsigned loU = 0u, hiU = 0x7F800000u;   // [0, +inf)
    int cLo = 0, cHi = NN;
    int laneLo = 0, laneHi = NREG;          // per-lane counts at loU / hiU
    float tPrev = t0; int cPrev = -1;

    // ---- quad-threshold opening probe (two packed DPP sums, latency-overlapped) ----
    if (t0 > 1e-30f) {
        float t1 = t0 * 0.75f, t2 = t0 * 0.95f, t3 = t0 * 1.15f, t4 = t0 * 1.40f;
        int l1 = 0, l2 = 0, l3 = 0, l4 = 0;
        #pragma unroll
        for (int r = 0; r < NREG; r++) {
            float v = d2r[r];
            l1 += (v < t1) ? 1 : 0;
            l2 += (v < t2) ? 1 : 0;
            l3 += (v < t3) ? 1 : 0;
            l4 += (v < t4) ? 1 : 0;
        }
        int s12 = wave_sum_dpp(l1 | (l2 << 16));
        int s34 = wave_sum_dpp(l3 | (l4 << 16));
        int c1 = s12 & 0xFFFF, c2 = s12 >> 16, c3 = s34 & 0xFFFF, c4 = s34 >> 16;
        if (c1 >= K)      { hiU = __float_as_uint(t1); cHi = c1; laneHi = l1; }
        else if (c2 >= K) { loU = __float_as_uint(t1); cLo = c1; laneLo = l1;
                            hiU = __float_as_uint(t2); cHi = c2; laneHi = l2; }
        else if (c3 >= K) { loU = __float_as_uint(t2); cLo = c2; laneLo = l2;
                            hiU = __float_as_uint(t3); cHi = c3; laneHi = l3; }
        else if (c4 >= K) { loU = __float_as_uint(t3); cLo = c3; laneLo = l3;
                            hiU = __float_as_uint(t4); cHi = c4; laneHi = l4; }
        else              { loU = __float_as_uint(t4); cLo = c4; laneLo = l4; }
        // anchor: nonzero count nearest K
        int bc = -1, bd = 0x7FFFFFFF; float bt = t0;
        int cs[4] = {c1, c2, c3, c4}; float ts[4] = {t1, t2, t3, t4};
        #pragma unroll
        for (int u = 0; u < 4; u++) {
            int d = cs[u] > K ? cs[u] - K : K - cs[u];
            if (cs[u] > 0 && d < bd) { bd = d; bc = cs[u]; bt = ts[u]; }
        }
        if (bc > 0) { tPrev = bt; cPrev = bc; }
        else        { tPrev = t4; cPrev = 0; }
    }

    // ---- dual-threshold bisection rounds ----
    int probes = 0;
    while (cHi - cLo > 64 && hiU - loU > 1u && probes < 20) {
        unsigned tAU = 0u, tBU = 0u;
        bool fell = false;
        if (cPrev > 0) {
            float g = tPrev * __fsqrt_rn((float)K / (float)cPrev);
            tAU = __float_as_uint(g * 0.88f); tBU = __float_as_uint(g * 1.18f);
        } else if (cPrev == 0) {
            tAU = __float_as_uint(tPrev * 3.0f); tBU = __float_as_uint(tPrev * 9.0f);
        } else fell = true;
        unsigned span = hiU - loU;
        if (fell || !(tAU > loU && tAU < hiU)) tAU = loU + span / 3u;
        if (tAU <= loU) tAU = loU + 1u;
        if (tAU >= hiU) tAU = hiU - 1u;
        if (fell || !(tBU >= tAU && tBU < hiU)) tBU = tAU + (hiU - tAU) / 2u;
        if (tBU < tAU) tBU = tAU;
        if (tBU >= hiU) tBU = hiU - 1u;

        float tA = __uint_as_float(tAU), tB = __uint_as_float(tBU);
        int clA = 0, clB = 0;
        #pragma unroll
        for (int r = 0; r < NREG; r++) {
            clA += (d2r[r] < tA) ? 1 : 0;
            clB += (d2r[r] < tB) ? 1 : 0;
        }
        int tot = wave_sum_dpp(clA | (clB << 16));   // sums fit 16 bits each (<= 2048)
        int cA = tot & 0xFFFF, cB = tot >> 16;

        if (cA >= K) { hiU = tAU; cHi = cA; laneHi = clA; }
        else {
            loU = tAU; cLo = cA; laneLo = clA;
            if (cB >= K) { hiU = tBU; cHi = cB; laneHi = clB; }
            else         { loU = tBU; cLo = cB; laneLo = clB; }
        }
        int dA = cA > K ? cA - K : K - cA;
        int dB = cB > K ? cB - K : K - cB;
        if (cA > 0 && dA <= dB) { tPrev = tA; cPrev = cA; }
        else                    { tPrev = tB; cPrev = cB; }
        probes++;
    }

    const float lo = __uint_as_float(loU);
    const float hi = __uint_as_float(hiU);
    const int  need = K - cLo;              // in [1, K]; window holds >= need values

    // ---- collect: counts known per lane; DPP scan -> sequential writes ----
    int c1c = laneLo;                       // # of my elems with v < lo (minus self if below)
    int c2c = laneHi - laneLo;              // # of my elems in [lo, hi)
    if (lane == (i & 63) && loU > 0u) c1c -= 1;  // self d2=0 < lo counted in laneLo
    int pk = c1c | (c2c << 16);
    int inc = wave_scan_dpp(pk);
    int excl = inc - pk;
    int tot  = __builtin_amdgcn_readlane(inc, 63);
    int b1 = excl & 0xFFFF;            // per-lane write base, below-window
    int b2 = excl >> 16;               // per-lane write base, candidates
    const int nbelow = tot & 0xFFFF;   // <= K-1
    int ecand = tot >> 16; if (ecand > 64) ecand = 64;
    #pragma unroll
    for (int r = 0; r < NREG; r++) {
        float v = d2r[r];
        int j = r * 64 + lane;
        if ((v < lo) & (j != i)) { isel[w][b1] = j; wsel[w][b1] = v; b1++; }
        else if ((v >= lo) & (v < hi)) { if (b2 < 64) candk[w][b2] = ((unsigned long long)__float_as_uint(v) << 32) | (unsigned)j; b2++; }
    }
    __builtin_amdgcn_wave_barrier();

    // ---- append `need` smallest candidates (value,index), skipping self ----
    int nsel;
    if (ecand == need && loU > 0u) {
        // fast path: window exactly fills remaining slots; self is below lo (excluded)
        if (lane < ecand) {
            int slot = nbelow + lane;
            if (slot < 64) {
                unsigned long long k2 = candk[w][lane];
                isel[w][slot] = (int)(k2 & 0xFFFFFFFFull);
                wsel[w][slot] = __uint_as_float((unsigned)(k2 >> 32));
            }
        }
        nsel = nbelow + ecand;
        if (nsel > 64) nsel = 64;
    } else {
        unsigned long long mykey = ~0ull;
        if (lane < ecand) mykey = candk[w][lane];
        int mr = 0;
        for (int u = 0; u < ecand; u++) {        // ds_read_b64 broadcast, conflict-free
            unsigned long long k2 = candk[w][u];
            mr += (k2 < mykey) ? 1 : 0;
        }
        int mj = (int)(mykey & 0xFFFFFFFFull);
        bool ps = (lane < ecand) & (mr < need) & (mj != i);
        unsigned long long ms = __ballot(ps);
        if (ps) {
            int slot = nbelow + __popcll(ms & ((1ull << lane) - 1ull));
            if (slot < 64) { isel[w][slot] = mj; wsel[w][slot] = __uint_as_float((unsigned)(mykey >> 32)); }
        }
        nsel = nbelow + __popcll(ms);
        if (nsel > 64) nsel = 64;                // expect K-1 = 39
    }
    __builtin_amdgcn_wave_barrier();
    if (lane < nsel) wsel[w][lane] = __expf(-wsel[w][lane]);
    __builtin_amdgcn_wave_barrier();

    // ---- weighted max / mean: lanes 0-21 do even m, lanes 32-53 odd m ----
    const float* fb = feats + (size_t)b * NN * PP;
    int g = lane >> 5, c = lane & 31;
    float mx = -INFINITY, sm = 0.f;
    if (c < PP) {
        #pragma unroll 8
        for (int m = g; m < nsel; m += 2) {
            int j = isel[w][m]; float wt = wsel[w][m];
            float f = fb[(size_t)j * PP + c];
            float wf = wt * f;
            mx = fmaxf(mx, wf); sm += wf;
        }
    }
    float mx2 = __shfl_xor(mx, 32, 64);
    float sm2 = __shfl_xor(sm, 32, 64);
    mx = fmaxf(mx, mx2); sm += sm2;
    if (g == 0 && c < PP) {
        urow[w][c]      = mx;
        urow[w][PP + c] = sm / (float)(K - 1);
    }
    __builtin_amdgcn_wave_barrier();

    // ---- epilogue: out[q][o] = tanh(xwo + [max|mean] . Wo[64:,o]), lanes 0-41 ----
    if (lane < OO) {
        float a0 = xw, a1 = 0.f, a2 = 0.f, a3 = 0.f;
        const float* wo = Wo + FF * OO + lane;   // rows 64..107, coalesced across lanes
        #pragma unroll
        for (int k4 = 0; k4 < (2 * PP) / 4; k4++) {
            float4 u = *((const float4*)&urow[w][k4 * 4]);   // ds_read_b128 broadcast
            a0 = fmaf(u.x, wo[(k4 * 4 + 0) * OO], a0);
            a1 = fmaf(u.y, wo[(k4 * 4 + 1) * OO], a1);
            a2 = fmaf(u.z, wo[(k4 * 4 + 2) * OO], a2);
            a3 = fmaf(u.w, wo[(k4 * 4 + 3) * OO], a3);
        }
        float acc = (a0 + a1) + (a2 + a3);
        float a = acc < -12.f ? -12.f : (acc > 12.f ? 12.f : acc);
        float e2 = __expf(2.f * a);
        out[(size_t)q * OO + lane] = (e2 - 1.f) / (e2 + 1.f);
    }
}

extern "C" void kernel_launch(void* const* d_in, const int* in_sizes, int n_in,
                              void* d_out, int out_size, void* d_ws, size_t ws_size,
                              hipStream_t stream) {
    const float* x  = (const float*)d_in[0];
    const float* Ws = (const float*)d_in[1];
    const float* bs = (const float*)d_in[2];
    const float* Wf = (const float*)d_in[3];
    const float* bf = (const float*)d_in[4];
    const float* Wo = (const float*)d_in[5];
    const float* bo = (const float*)d_in[6];
    const int*   nn = (const int*)d_in[7];
    float* out = (float*)d_out;

    float* coords = (float*)d_ws;                              // 16*2048*4  = 512 KB
    float* feats  = coords + (size_t)BB * NN * SS;             // 16*2048*22 = 2.75 MB
    float* xwo    = feats  + (size_t)BB * NN * PP;             // 32768*42   = 5.5 MB

    precompute_kernel<<<(BB * NN) / 256, 256, 0, stream>>>(x, Ws, bs, Wf, bf, coords, feats);
    xwo_kernel<<<(BB * NN * OO + 255) / 256, 256, 0, stream>>>(x, Wo, bo, xwo);
    knn_out_kernel<<<(BB * NN) / 2, 128, 0, stream>>>(coords, feats, xwo, Wo, nn, out);
}

// Round 15
// 182.433 us; speedup vs baseline: 1.0993x; 1.0993x over previous
//
#include <hip/hip_runtime.h>
#include <math.h>

#define BB 16
#define NN 2048
#define FF 64
#define SS 4
#define PP 22
#define OO 42
#define FPDIM (FF + 2*PP)   // 108
#define NREG 32             // all 2048/64 d2 values kept in VGPRs per lane
#define PREBLK 128                     // blocks 0..127: coords/feats rows
#define XWOBLK ((BB*NN*21 + 255)/256)  // 2688 blocks: xwo o-pairs

__device__ __forceinline__ float readfirstlane_f32(float v) {
    // value-preserving wave-uniform broadcast (builtin is int->int; must pass bits!)
    return __uint_as_float((unsigned)__builtin_amdgcn_readfirstlane((int)__float_as_uint(v)));
}

// canonical GCN wave64 inclusive scan via DPP: row_shr 1/2/4/8 (bound_ctrl -> OOB reads 0),
// then row_bcast:15 into rows 1,3 and row_bcast:31 into rows 2,3. [R11/R12-validated]
__device__ __forceinline__ int wave_scan_dpp(int x) {
    x += __builtin_amdgcn_update_dpp(0, x, 0x111, 0xf, 0xf, true);  // row_shr:1
    x += __builtin_amdgcn_update_dpp(0, x, 0x112, 0xf, 0xf, true);  // row_shr:2
    x += __builtin_amdgcn_update_dpp(0, x, 0x114, 0xf, 0xf, true);  // row_shr:4
    x += __builtin_amdgcn_update_dpp(0, x, 0x118, 0xf, 0xf, true);  // row_shr:8
    x += __builtin_amdgcn_update_dpp(0, x, 0x142, 0xa, 0xf, true);  // row_bcast:15 -> rows 1,3
    x += __builtin_amdgcn_update_dpp(0, x, 0x143, 0xc, 0xf, true);  // row_bcast:31 -> rows 2,3
    return x;
}
__device__ __forceinline__ int wave_sum_dpp(int x) {
    return __builtin_amdgcn_readlane(wave_scan_dpp(x), 63);
}
// float wave sum: same chain in float domain (0-bits = 0.0f additive identity)
__device__ __forceinline__ float wave_fsum_dpp(float x) {
    float t;
    t = __uint_as_float((unsigned)__builtin_amdgcn_update_dpp(0, (int)__float_as_uint(x), 0x111, 0xf, 0xf, true)); x += t;
    t = __uint_as_float((unsigned)__builtin_amdgcn_update_dpp(0, (int)__float_as_uint(x), 0x112, 0xf, 0xf, true)); x += t;
    t = __uint_as_float((unsigned)__builtin_amdgcn_update_dpp(0, (int)__float_as_uint(x), 0x114, 0xf, 0xf, true)); x += t;
    t = __uint_as_float((unsigned)__builtin_amdgcn_update_dpp(0, (int)__float_as_uint(x), 0x118, 0xf, 0xf, true)); x += t;
    t = __uint_as_float((unsigned)__builtin_amdgcn_update_dpp(0, (int)__float_as_uint(x), 0x142, 0xa, 0xf, true)); x += t;
    t = __uint_as_float((unsigned)__builtin_amdgcn_update_dpp(0, (int)__float_as_uint(x), 0x143, 0xc, 0xf, true)); x += t;
    return __uint_as_float((unsigned)__builtin_amdgcn_readlane((int)__float_as_uint(x), 63));
}

// ---- Kernel 1 (fused): blocks 0..127 -> coords/feats rows; blocks 128.. -> xwo o-pairs ----
// xwo path: one thread per (row, output-pair): 16 float4 x-loads + 64 float2 Wo-loads
// + 128 fma + 1 float2 store (81 VMEM insts vs 256 for the same work one-per-element).
__global__ __launch_bounds__(256) void prep_kernel(
    const float* __restrict__ x, const float* __restrict__ Ws, const float* __restrict__ bs,
    const float* __restrict__ Wf, const float* __restrict__ bf,
    const float* __restrict__ Wo, const float* __restrict__ bo,
    float* __restrict__ coords, float* __restrict__ feats, float* __restrict__ xwo)
{
    if (blockIdx.x >= PREBLK) {
        // ---- xwo[row][2p..2p+1] = x[row] . Wo[:64, 2p..2p+1] + bo ----
        int idx = (blockIdx.x - PREBLK) * 256 + threadIdx.x;   // row*21 + p
        if (idx >= BB * NN * 21) return;
        int row = idx / 21;                // magic-mul division
        int p   = idx - row * 21;
        int o   = p * 2;
        const float4* xr = (const float4*)(x + (size_t)row * FF);
        float a0 = bo[o], b0 = bo[o + 1], a1 = 0.f, b1 = 0.f;
        #pragma unroll
        for (int k4 = 0; k4 < FF / 4; k4++) {
            float4 xv = xr[k4];            // broadcast within row-group of lanes
            const float* wb = Wo + (k4 * 4) * OO + o;
            float2 w0 = *((const float2*)(wb));
            float2 w1 = *((const float2*)(wb + OO));
            float2 w2 = *((const float2*)(wb + 2 * OO));
            float2 w3 = *((const float2*)(wb + 3 * OO));
            a0 = fmaf(xv.x, w0.x, a0); b0 = fmaf(xv.x, w0.y, b0);
            a1 = fmaf(xv.y, w1.x, a1); b1 = fmaf(xv.y, w1.y, b1);
            a0 = fmaf(xv.z, w2.x, a0); b0 = fmaf(xv.z, w2.y, b0);
            a1 = fmaf(xv.w, w3.x, a1); b1 = fmaf(xv.w, w3.y, b1);
        }
        *((float2*)(xwo + (size_t)idx * 2)) = make_float2(a0 + a1, b0 + b1);   // coalesced
        return;
    }

    // ---- coords = x@W_s + b_s ; feats = x@W_f + b_f ----
    int row = blockIdx.x * 256 + threadIdx.x;   // 0 .. B*N-1
    if (row >= BB * NN) return;

    const float4* x4 = (const float4*)(x + (size_t)row * FF);
    float c0 = bs[0], c1 = bs[1], c2 = bs[2], c3 = bs[3];
    float f[PP];
    #pragma unroll
    for (int c = 0; c < PP; c++) f[c] = bf[c];

    #pragma unroll
    for (int k4 = 0; k4 < FF / 4; k4++) {
        float4 xv = x4[k4];
        float xs[4] = {xv.x, xv.y, xv.z, xv.w};
        #pragma unroll
        for (int r = 0; r < 4; r++) {
            int k = k4 * 4 + r;
            float xk = xs[r];
            c0 = fmaf(xk, Ws[k * SS + 0], c0);
            c1 = fmaf(xk, Ws[k * SS + 1], c1);
            c2 = fmaf(xk, Ws[k * SS + 2], c2);
            c3 = fmaf(xk, Ws[k * SS + 3], c3);
            #pragma unroll
            for (int c = 0; c < PP; c++) f[c] = fmaf(xk, Wf[k * PP + c], f[c]);
        }
    }
    float4* cp = (float4*)(coords + (size_t)row * SS);
    *cp = make_float4(c0, c1, c2, c3);
    float* fo = feats + (size_t)row * PP;
    #pragma unroll
    for (int c = 0; c < PP; c++) fo[c] = f[c];
}

// ---- Kernel 2: wave-per-query kNN + aggregate + fused (neighbor-part) matvec/tanh ----
// (128,4) -> 8 waves/EU. All 32 d2 in VGPRs. Quad opening probe + dual bisection (DPP sums);
// DPP scan collect; tie-rank with fast path; epilogue only covers k=64..107 (x-part hoisted).
// [R13/R14-measured: ~91us, VGPR 32, occupancy 75%]
__global__ __launch_bounds__(128, 4) void knn_out_kernel(
    const float* __restrict__ coords, const float* __restrict__ feats,
    const float* __restrict__ xwo, const float* __restrict__ Wo,
    const int* __restrict__ nnbr, float* __restrict__ out)
{
    const int lane = threadIdx.x & 63;
    const int w    = threadIdx.x >> 6;
    const int q    = blockIdx.x * 2 + w;       // 0..32767
    const int b    = q >> 11;
    const int i    = q & (NN - 1);

    int K = *nnbr; K = K < 2 ? 2 : (K > 64 ? 64 : K);

    __shared__ int   isel[2][64];
    __shared__ float wsel[2][64];
    __shared__ unsigned long long candk[2][64];   // (d2bits<<32)|j packed keys
    __shared__ __align__(16) float urow[2][48];   // [max | mean], 44 used

    // prefetch the precomputed x-part of the output (overlaps the distance phase)
    float xw = 0.f;
    if (lane < OO) xw = xwo[(size_t)q * OO + lane];

    const float4* cb = (const float4*)(coords + (size_t)b * NN * SS);
    float4 qv = cb[i];
    const float qx = readfirstlane_f32(qv.x);
    const float qy = readfirstlane_f32(qv.y);
    const float qz = readfirstlane_f32(qv.z);
    const float qw = readfirstlane_f32(qv.w);

    // ---- distances: all 2048 kept in 32 VGPRs/lane; track per-lane min ----
    float d2r[NREG];
    float lmin = INFINITY;
    #pragma unroll 4
    for (int r = 0; r < NREG; r++) {
        float4 c = cb[r * 64 + lane];
        float d0 = qx - c.x, d1 = qy - c.y, d2 = qz - c.z, d3 = qw - c.w;
        float v = d0 * d0 + d1 * d1 + d2 * d2 + d3 * d3;
        d2r[r] = v;
        lmin = fminf(lmin, v);
    }

    // ---- first-probe estimator: mean of per-lane minima ~ K/N quantile (DPP sum) ----
    float t0 = wave_fsum_dpp(lmin) * (1.0f / 64.0f);

    // ---- selection state: invariant cnt_lt(lo) < K <= cnt_lt(hi) ----
    unsigned loU = 0u, hiU = 0x7F800000u;   // [0, +inf)
    int cLo = 0, cHi = NN;
    int laneLo = 0, laneHi = NREG;          // per-lane counts at loU / hiU
    float tPrev = t0; int cPrev = -1;

    // ---- quad-threshold opening probe (two packed DPP sums, latency-overlapped) ----
    if (t0 > 1e-30f) {
        float t1 = t0 * 0.75f, t2 = t0 * 0.95f, t3 = t0 * 1.15f, t4 = t0 * 1.40f;
        int l1 = 0, l2 = 0, l3 = 0, l4 = 0;
        #pragma unroll
        for (int r = 0; r < NREG; r++) {
            float v = d2r[r];
            l1 += (v < t1) ? 1 : 0;
            l2 += (v < t2) ? 1 : 0;
            l3 += (v < t3) ? 1 : 0;
            l4 += (v < t4) ? 1 : 0;
        }
        int s12 = wave_sum_dpp(l1 | (l2 << 16));
        int s34 = wave_sum_dpp(l3 | (l4 << 16));
        int c1 = s12 & 0xFFFF, c2 = s12 >> 16, c3 = s34 & 0xFFFF, c4 = s34 >> 16;
        if (c1 >= K)      { hiU = __float_as_uint(t1); cHi = c1; laneHi = l1; }
        else if (c2 >= K) { loU = __float_as_uint(t1); cLo = c1; laneLo = l1;
                            hiU = __float_as_uint(t2); cHi = c2; laneHi = l2; }
        else if (c3 >= K) { loU = __float_as_uint(t2); cLo = c2; laneLo = l2;
                            hiU = __float_as_uint(t3); cHi = c3; laneHi = l3; }
        else if (c4 >= K) { loU = __float_as_uint(t3); cLo = c3; laneLo = l3;
                            hiU = __float_as_uint(t4); cHi = c4; laneHi = l4; }
        else              { loU = __float_as_uint(t4); cLo = c4; laneLo = l4; }
        // anchor: nonzero count nearest K
        int bc = -1, bd = 0x7FFFFFFF; float bt = t0;
        int cs[4] = {c1, c2, c3, c4}; float ts[4] = {t1, t2, t3, t4};
        #pragma unroll
        for (int u = 0; u < 4; u++) {
            int d = cs[u] > K ? cs[u] - K : K - cs[u];
            if (cs[u] > 0 && d < bd) { bd = d; bc = cs[u]; bt = ts[u]; }
        }
        if (bc > 0) { tPrev = bt; cPrev = bc; }
        else        { tPrev = t4; cPrev = 0; }
    }

    // ---- dual-threshold bisection rounds ----
    int probes = 0;
    while (cHi - cLo > 64 && hiU - loU > 1u && probes < 20) {
        unsigned tAU = 0u, tBU = 0u;
        bool fell = false;
        if (cPrev > 0) {
            float g = tPrev * __fsqrt_rn((float)K / (float)cPrev);
            tAU = __float_as_uint(g * 0.88f); tBU = __float_as_uint(g * 1.18f);
        } else if (cPrev == 0) {
            tAU = __float_as_uint(tPrev * 3.0f); tBU = __float_as_uint(tPrev * 9.0f);
        } else fell = true;
        unsigned span = hiU - loU;
        if (fell || !(tAU > loU && tAU < hiU)) tAU = loU + span / 3u;
        if (tAU <= loU) tAU = loU + 1u;
        if (tAU >= hiU) tAU = hiU - 1u;
        if (fell || !(tBU >= tAU && tBU < hiU)) tBU = tAU + (hiU - tAU) / 2u;
        if (tBU < tAU) tBU = tAU;
        if (tBU >= hiU) tBU = hiU - 1u;

        float tA = __uint_as_float(tAU), tB = __uint_as_float(tBU);
        int clA = 0, clB = 0;
        #pragma unroll
        for (int r = 0; r < NREG; r++) {
            clA += (d2r[r] < tA) ? 1 : 0;
            clB += (d2r[r] < tB) ? 1 : 0;
        }
        int tot = wave_sum_dpp(clA | (clB << 16));   // sums fit 16 bits each (<= 2048)
        int cA = tot & 0xFFFF, cB = tot >> 16;

        if (cA >= K) { hiU = tAU; cHi = cA; laneHi = clA; }
        else {
            loU = tAU; cLo = cA; laneLo = clA;
            if (cB >= K) { hiU = tBU; cHi = cB; laneHi = clB; }
            else         { loU = tBU; cLo = cB; laneLo = clB; }
        }
        int dA = cA > K ? cA - K : K - cA;
        int dB = cB > K ? cB - K : K - cB;
        if (cA > 0 && dA <= dB) { tPrev = tA; cPrev = cA; }
        else                    { tPrev = tB; cPrev = cB; }
        probes++;
    }

    const float lo = __uint_as_float(loU);
    const float hi = __uint_as_float(hiU);
    const int  need = K - cLo;              // in [1, K]; window holds >= need values

    // ---- collect: counts known per lane; DPP scan -> sequential writes ----
    int c1c = laneLo;                       // # of my elems with v < lo (minus self if below)
    int c2c = laneHi - laneLo;              // # of my elems in [lo, hi)
    if (lane == (i & 63) && loU > 0u) c1c -= 1;  // self d2=0 < lo counted in laneLo
    int pk = c1c | (c2c << 16);
    int inc = wave_scan_dpp(pk);
    int excl = inc - pk;
    int tot  = __builtin_amdgcn_readlane(inc, 63);
    int b1 = excl & 0xFFFF;            // per-lane write base, below-window
    int b2 = excl >> 16;               // per-lane write base, candidates
    const int nbelow = tot & 0xFFFF;   // <= K-1
    int ecand = tot >> 16; if (ecand > 64) ecand = 64;
    #pragma unroll
    for (int r = 0; r < NREG; r++) {
        float v = d2r[r];
        int j = r * 64 + lane;
        if ((v < lo) & (j != i)) { isel[w][b1] = j; wsel[w][b1] = v; b1++; }
        else if ((v >= lo) & (v < hi)) { if (b2 < 64) candk[w][b2] = ((unsigned long long)__float_as_uint(v) << 32) | (unsigned)j; b2++; }
    }
    __builtin_amdgcn_wave_barrier();

    // ---- append `need` smallest candidates (value,index), skipping self ----
    int nsel;
    if (ecand == need && loU > 0u) {
        // fast path: window exactly fills remaining slots; self is below lo (excluded)
        if (lane < ecand) {
            int slot = nbelow + lane;
            if (slot < 64) {
                unsigned long long k2 = candk[w][lane];
                isel[w][slot] = (int)(k2 & 0xFFFFFFFFull);
                wsel[w][slot] = __uint_as_float((unsigned)(k2 >> 32));
            }
        }
        nsel = nbelow + ecand;
        if (nsel > 64) nsel = 64;
    } else {
        unsigned long long mykey = ~0ull;
        if (lane < ecand) mykey = candk[w][lane];
        int mr = 0;
        for (int u = 0; u < ecand; u++) {        // ds_read_b64 broadcast, conflict-free
            unsigned long long k2 = candk[w][u];
            mr += (k2 < mykey) ? 1 : 0;
        }
        int mj = (int)(mykey & 0xFFFFFFFFull);
        bool ps = (lane < ecand) & (mr < need) & (mj != i);
        unsigned long long ms = __ballot(ps);
        if (ps) {
            int slot = nbelow + __popcll(ms & ((1ull << lane) - 1ull));
            if (slot < 64) { isel[w][slot] = mj; wsel[w][slot] = __uint_as_float((unsigned)(mykey >> 32)); }
        }
        nsel = nbelow + __popcll(ms);
        if (nsel > 64) nsel = 64;                // expect K-1 = 39
    }
    __builtin_amdgcn_wave_barrier();
    if (lane < nsel) wsel[w][lane] = __expf(-wsel[w][lane]);
    __builtin_amdgcn_wave_barrier();

    // ---- weighted max / mean: lanes 0-21 do even m, lanes 32-53 odd m ----
    const float* fb = feats + (size_t)b * NN * PP;
    int g = lane >> 5, c = lane & 31;
    float mx = -INFINITY, sm = 0.f;
    if (c < PP) {
        #pragma unroll 8
        for (int m = g; m < nsel; m += 2) {
            int j = isel[w][m]; float wt = wsel[w][m];
            float f = fb[(size_t)j * PP + c];
            float wf = wt * f;
            mx = fmaxf(mx, wf); sm += wf;
        }
    }
    float mx2 = __shfl_xor(mx, 32, 64);
    float sm2 = __shfl_xor(sm, 32, 64);
    mx = fmaxf(mx, mx2); sm += sm2;
    if (g == 0 && c < PP) {
        urow[w][c]      = mx;
        urow[w][PP + c] = sm / (float)(K - 1);
    }
    __builtin_amdgcn_wave_barrier();

    // ---- epilogue: out[q][o] = tanh(xwo + [max|mean] . Wo[64:,o]), lanes 0-41 ----
    if (lane < OO) {
        float a0 = xw, a1 = 0.f, a2 = 0.f, a3 = 0.f;
        const float* wo = Wo + FF * OO + lane;   // rows 64..107, coalesced across lanes
        #pragma unroll
        for (int k4 = 0; k4 < (2 * PP) / 4; k4++) {
            float4 u = *((const float4*)&urow[w][k4 * 4]);   // ds_read_b128 broadcast
            a0 = fmaf(u.x, wo[(k4 * 4 + 0) * OO], a0);
            a1 = fmaf(u.y, wo[(k4 * 4 + 1) * OO], a1);
            a2 = fmaf(u.z, wo[(k4 * 4 + 2) * OO], a2);
            a3 = fmaf(u.w, wo[(k4 * 4 + 3) * OO], a3);
        }
        float acc = (a0 + a1) + (a2 + a3);
        float a = acc < -12.f ? -12.f : (acc > 12.f ? 12.f : acc);
        float e2 = __expf(2.f * a);
        out[(size_t)q * OO + lane] = (e2 - 1.f) / (e2 + 1.f);
    }
}

extern "C" void kernel_launch(void* const* d_in, const int* in_sizes, int n_in,
                              void* d_out, int out_size, void* d_ws, size_t ws_size,
                              hipStream_t stream) {
    const float* x  = (const float*)d_in[0];
    const float* Ws = (const float*)d_in[1];
    const float* bs = (const float*)d_in[2];
    const float* Wf = (const float*)d_in[3];
    const float* bf = (const float*)d_in[4];
    const float* Wo = (const float*)d_in[5];
    const float* bo = (const float*)d_in[6];
    const int*   nn = (const int*)d_in[7];
    float* out = (float*)d_out;

    float* coords = (float*)d_ws;                              // 16*2048*4  = 512 KB
    float* feats  = coords + (size_t)BB * NN * SS;             // 16*2048*22 = 2.75 MB
    float* xwo    = feats  + (size_t)BB * NN * PP;             // 32768*42   = 5.5 MB

    prep_kernel<<<PREBLK + XWOBLK, 256, 0, stream>>>(x, Ws, bs, Wf, bf, Wo, bo, coords, feats, xwo);
    knn_out_kernel<<<(BB * NN) / 2, 128, 0, stream>>>(coords, feats, xwo, Wo, nn, out);
}